// Round 1
// baseline (249.941 us; speedup 1.0000x reference)
//
#include <hip/hip_runtime.h>
#include <stdint.h>

// Problem constants
#define DIM    1024
#define RANK   16
#define M_TOT  8192          // 2*4096 rows of x
#define N_TOT  3072          // 3*DIM output features
#define K_TOT  1024

#define BM 128
#define BN 128
#define BK 64

typedef __attribute__((ext_vector_type(8))) short  s8v;   // 8 x bf16 (raw bits)
typedef __attribute__((ext_vector_type(4))) float  f4v;   // MFMA acc

__device__ __forceinline__ unsigned short f2bf(float f) {
    union { float f; unsigned int u; } v; v.f = f;
    unsigned int u = v.u;
    u += 0x7FFFu + ((u >> 16) & 1u);   // round-to-nearest-even
    return (unsigned short)(u >> 16);
}

// ---------------- Kernel 1: x fp32 -> bf16 ----------------
__global__ void cvt_x(const float4* __restrict__ x, ushort4* __restrict__ xb, int n4) {
    int i = blockIdx.x * blockDim.x + threadIdx.x;
    if (i < n4) {
        float4 v = x[i];
        ushort4 o;
        o.x = f2bf(v.x); o.y = f2bf(v.y); o.z = f2bf(v.z); o.w = f2bf(v.w);
        xb[i] = o;
    }
}

// ---------------- Kernel 2: fold LoRA into weights, fp32 -> bf16 ----------------
// W_eff[o][d] = W[o][d] + alpha * sum_r B_sel[o%1024][r] * A_sel[r][d]
__global__ void fold_w(const float* __restrict__ W,
                       const float* __restrict__ Aq, const float* __restrict__ Bq,
                       const float* __restrict__ Ak, const float* __restrict__ Bk,
                       const float* __restrict__ Av, const float* __restrict__ Bv,
                       const float* __restrict__ alpha_p,
                       unsigned short* __restrict__ Wb) {
    const int o   = blockIdx.x;          // 0..3071
    const int tid = threadIdx.x;         // 256
    const int sel  = o >> 10;            // 0=q 1=k 2=v
    const int orow = o & 1023;
    const float* Am = (sel == 0) ? Aq : (sel == 1) ? Ak : Av;  // [RANK, DIM]
    const float* Bm = (sel == 0) ? Bq : (sel == 1) ? Bk : Bv;  // [DIM, RANK]

    __shared__ float sb[RANK];
    if (tid < RANK) sb[tid] = alpha_p[0] * Bm[orow * RANK + tid];
    __syncthreads();

    for (int d = tid; d < DIM; d += 256) {
        float acc = W[o * DIM + d];
        #pragma unroll
        for (int r = 0; r < RANK; ++r)
            acc += sb[r] * Am[r * DIM + d];
        Wb[o * DIM + d] = f2bf(acc);
    }
}

// ---------------- Kernel 3: bf16 MFMA GEMM, C = Xb * Wb^T + bias ----------------
// Xb: [M_TOT, K_TOT] bf16 row-major; Wb: [N_TOT, K_TOT] bf16 row-major (NT gemm)
// LDS layout: fragment-ordered chunks. Tile [128 x 64] = 16 chunks of 1024 B.
// Chunk c holds rows (c>>1)*16 + (l&15), k = (c&1)*32 + (l>>4)*8 .. +8, in lane
// order (lane l owns bytes [c*1024 + l*16, +16)) -> satisfies global_load_lds'
// wave-uniform-base + lane*16 constraint AND makes ds_read_b128 conflict-free.
__global__ __launch_bounds__(256, 2)
void gemm_bt(const unsigned short* __restrict__ Xb,
             const unsigned short* __restrict__ Wb,
             const float* __restrict__ bias,
             float* __restrict__ out) {
    __shared__ __align__(16) unsigned short As[BM * BK];  // 16 KB
    __shared__ __align__(16) unsigned short Bs[BN * BK];  // 16 KB

    const int tid  = threadIdx.x;
    const int wave = tid >> 6;       // 0..3
    const int lane = tid & 63;
    const int l15  = lane & 15;
    const int lq   = lane >> 4;      // 0..3
    const int wr   = wave >> 1;      // wave row quadrant (0..1)
    const int wc   = wave & 1;       // wave col quadrant (0..1)

    const int bm = blockIdx.x;       // 0..63   (M tiles)
    const int bn = blockIdx.y;       // 0..23   (N tiles)

    // Per-lane global staging pointers for this wave's 4 chunks (of 16)
    const unsigned short* aptr[4];
    const unsigned short* bptr[4];
    #pragma unroll
    for (int u = 0; u < 4; ++u) {
        const int c   = wave * 4 + u;
        const int row = ((c >> 1) << 4) + l15;       // 0..127
        const int col = ((c & 1) << 5) + (lq << 3);  // 0..56
        aptr[u] = Xb + (size_t)(bm * BM + row) * K_TOT + col;
        bptr[u] = Wb + (size_t)(bn * BN + row) * K_TOT + col;
    }

    f4v acc[4][4] = {};

    for (int kk = 0; kk < K_TOT; kk += BK) {
        __syncthreads();   // all waves done reading LDS from prev iter
        #pragma unroll
        for (int u = 0; u < 4; ++u) {
            const int c = wave * 4 + u;
            __builtin_amdgcn_global_load_lds(
                (const __attribute__((address_space(1))) void*)(aptr[u]),
                (__attribute__((address_space(3))) void*)(&As[c * 512]),
                16, 0, 0);
            __builtin_amdgcn_global_load_lds(
                (const __attribute__((address_space(1))) void*)(bptr[u]),
                (__attribute__((address_space(3))) void*)(&Bs[c * 512]),
                16, 0, 0);
            aptr[u] += BK;
            bptr[u] += BK;
        }
        __syncthreads();   // staging landed (vmcnt(0) drained before barrier)

        const s8v* Av = (const s8v*)As;
        const s8v* Bv = (const s8v*)Bs;
        #pragma unroll
        for (int t = 0; t < 2; ++t) {          // two k-steps of 32 within BK=64
            s8v af[4], bf[4];
            #pragma unroll
            for (int i = 0; i < 4; ++i) {
                const int ia = wr * 4 + i;     // A row-tile index 0..7
                const int jb = wc * 4 + i;     // B row-tile index 0..7
                af[i] = Av[(ia * 2 + t) * 64 + lane];
                bf[i] = Bv[(jb * 2 + t) * 64 + lane];
            }
            #pragma unroll
            for (int i = 0; i < 4; ++i)
                #pragma unroll
                for (int j = 0; j < 4; ++j)
                    acc[i][j] = __builtin_amdgcn_mfma_f32_16x16x32_bf16(
                        af[i], bf[j], acc[i][j], 0, 0, 0);
        }
    }

    // Epilogue: C/D layout col = lane&15, row = (lane>>4)*4 + reg  [m89]
    const int col_base = bn * BN + wc * 64;
    const int row_base = bm * BM + wr * 64 + lq * 4;
    #pragma unroll
    for (int j = 0; j < 4; ++j) {
        const int col = col_base + j * 16 + l15;
        const float bv = bias[col];
        #pragma unroll
        for (int i = 0; i < 4; ++i) {
            const int row = row_base + i * 16;
            #pragma unroll
            for (int r = 0; r < 4; ++r)
                out[(size_t)(row + r) * N_TOT + col] = acc[i][j][r] + bv;
        }
    }
}

extern "C" void kernel_launch(void* const* d_in, const int* in_sizes, int n_in,
                              void* d_out, int out_size, void* d_ws, size_t ws_size,
                              hipStream_t stream) {
    const float* x     = (const float*)d_in[0];   // [2,4096,1024]
    const float* W     = (const float*)d_in[1];   // [3072,1024]
    const float* b     = (const float*)d_in[2];   // [3072]
    const float* Aq    = (const float*)d_in[3];
    const float* Bq    = (const float*)d_in[4];
    const float* Ak    = (const float*)d_in[5];
    const float* Bk    = (const float*)d_in[6];
    const float* Av    = (const float*)d_in[7];
    const float* Bv    = (const float*)d_in[8];
    const float* alpha = (const float*)d_in[9];
    float* out = (float*)d_out;

    unsigned short* xb = (unsigned short*)d_ws;                              // 16 MB
    unsigned short* Wb = (unsigned short*)((char*)d_ws + (size_t)M_TOT * K_TOT * 2); // +6 MB

    const int n4 = (M_TOT * K_TOT) / 4;   // 2097152
    cvt_x<<<n4 / 256, 256, 0, stream>>>((const float4*)x, (ushort4*)xb, n4);
    fold_w<<<N_TOT, 256, 0, stream>>>(W, Aq, Bq, Ak, Bk, Av, Bv, alpha, Wb);

    dim3 grid(M_TOT / BM, N_TOT / BN);    // 64 x 24 = 1536 blocks
    gemm_bt<<<grid, 256, 0, stream>>>(xb, Wb, b, out);
}